// Round 6
// baseline (222.897 us; speedup 1.0000x reference)
//
#include <hip/hip_runtime.h>

typedef unsigned short u16;
typedef unsigned int u32;

typedef __attribute__((ext_vector_type(4))) float f32x4;
typedef __attribute__((ext_vector_type(8))) short bf16x8;

// ---- helpers ----------------------------------------------------------

__device__ inline u16 f2b(float f) {
  union { float f; u32 u; } x; x.f = f;
  u32 u = x.u;
  u32 r = (u + 0x7fffu + ((u >> 16) & 1u)) >> 16;   // round-nearest-even
  return (u16)r;
}

__device__ inline u32 cvtpk(float lo, float hi) {
  u32 r;
  asm("v_cvt_pk_bf16_f32 %0, %1, %2" : "=v"(r) : "v"(lo), "v"(hi));
  return r;
}

__device__ inline void gload_lds16(const void* g, void* l) {
  __builtin_amdgcn_global_load_lds(
      (const __attribute__((address_space(1))) u32*)g,
      (__attribute__((address_space(3))) u32*)l, 16, 0, 0);
}

// ---- fp32 -> bf16 convert (x + 4 weights in one dispatch) -------------
// blocks [0,8192): x ; [8192,12288): weights (wq|wk|wv|wp contiguous)

__global__ __launch_bounds__(256) void cvt_all(const float* __restrict__ x,
                                               const float* __restrict__ w0,
                                               const float* __restrict__ w1,
                                               const float* __restrict__ w2,
                                               const float* __restrict__ w3,
                                               u16* __restrict__ xo,
                                               u16* __restrict__ wo) {
  int b = blockIdx.x;
  const float* s;
  u16* d;
  int i;
  if (b < 8192) {
    s = x; d = xo; i = b * 256 + threadIdx.x;
  } else {
    int m = (b - 8192) >> 10;
    s = (m == 0) ? w0 : (m == 1) ? w1 : (m == 2) ? w2 : w3;
    d = wo + (size_t)m * 1048576;
    i = ((b - 8192) & 1023) * 256 + threadIdx.x;
  }
  float4 v = ((const float4*)s)[i];
  ushort4 o;
  o.x = f2b(v.x); o.y = f2b(v.y); o.z = f2b(v.z); o.w = f2b(v.w);
  ((ushort4*)d)[i] = o;
}

// ---- fused QKV GEMM ----------------------------------------------------
// A[8192][1024] bf16, W[3072][1024] bf16 (wq|wk|wv rows).
// col<1024 -> Q bf16 [bh][t][d] scaled by qscale; col<2048 -> K same layout;
// col>=2048 -> V^T bf16 [bh][d][t] (ushort4-packed along t).
// grid (24, 64), 256 thr.

__global__ __launch_bounds__(256) void gemm_qkv(const u16* __restrict__ A,
                                                const u16* __restrict__ W,
                                                const float* __restrict__ bq,
                                                const float* __restrict__ bk,
                                                const float* __restrict__ bv,
                                                u16* __restrict__ outQ,
                                                u16* __restrict__ outK,
                                                u16* __restrict__ outVt,
                                                float qscale) {
  __shared__ u16 sA[128 * 32];
  __shared__ u16 sB[128 * 32];

  const int K = 1024;
  const int t = threadIdx.x;
  const int lane = t & 63;
  const int w = t >> 6;
  const int wr = w >> 1, wc = w & 1;
  const int lr = lane & 15, lg = lane >> 4;

  // bijective XCD-chunked swizzle (1536 blocks, 1536%8==0)
  int bid = blockIdx.y * 24 + blockIdx.x;
  int swz = (bid & 7) * 192 + (bid >> 3);
  const int mBase = (swz / 24) * 128;
  const int nBase = (swz % 24) * 128;

  f32x4 zero = {0.f, 0.f, 0.f, 0.f};
  f32x4 acc[4][4];
#pragma unroll
  for (int i = 0; i < 4; ++i)
#pragma unroll
    for (int j = 0; j < 4; ++j) acc[i][j] = zero;

  const int rA = t >> 2;
  const int cA = (t & 3) * 8;

  for (int k0 = 0; k0 < K; k0 += 32) {
#pragma unroll
    for (int i = 0; i < 2; ++i) {
      gload_lds16(A + (size_t)(mBase + i * 64 + rA) * K + k0 + cA,
                  &sA[i * 2048 + t * 8]);
      gload_lds16(W + (size_t)(nBase + i * 64 + rA) * K + k0 + cA,
                  &sB[i * 2048 + t * 8]);
    }
    __syncthreads();

    bf16x8 af[4], bf[4];
#pragma unroll
    for (int i = 0; i < 4; ++i)
      af[i] = *(const bf16x8*)&sA[(wr * 64 + i * 16 + lr) * 32 + lg * 8];
#pragma unroll
    for (int j = 0; j < 4; ++j)
      bf[j] = *(const bf16x8*)&sB[(wc * 64 + j * 16 + lr) * 32 + lg * 8];

#pragma unroll
    for (int i = 0; i < 4; ++i)
#pragma unroll
      for (int j = 0; j < 4; ++j)
        acc[i][j] = __builtin_amdgcn_mfma_f32_16x16x32_bf16(af[i], bf[j],
                                                            acc[i][j], 0, 0, 0);
    __syncthreads();
  }

  const int mode = nBase >> 10;       // 0=Q 1=K 2=V (128 | 1024)
  const float* bias = (mode == 0) ? bq : (mode == 1) ? bk : bv;
  const float scl = (mode == 0) ? qscale : 1.f;

#pragma unroll
  for (int i = 0; i < 4; ++i) {
    int row = mBase + wr * 64 + i * 16 + lg * 4;     // row % 4 == 0
    int b = row >> 11, tp = row & 2047;
#pragma unroll
    for (int j = 0; j < 4; ++j) {
      int col = nBase + wc * 64 + j * 16 + lr;
      int ncol = col & 1023;
      int h = ncol >> 6, dd = ncol & 63;
      float bv_ = bias[ncol];
      if (mode == 2) {
        ushort4 o;
        o.x = f2b(acc[i][j][0] + bv_);
        o.y = f2b(acc[i][j][1] + bv_);
        o.z = f2b(acc[i][j][2] + bv_);
        o.w = f2b(acc[i][j][3] + bv_);
        *(ushort4*)(outVt + ((size_t)((b * 16 + h) * 64 + dd)) * 2048 + tp) = o;
      } else {
        u16* ob = (mode == 0) ? outQ : outK;
#pragma unroll
        for (int r = 0; r < 4; ++r)
          ob[(((size_t)(b * 16 + h) * 2048) + tp + r) * 64 + dd] =
              f2b((acc[i][j][r] + bv_) * scl);
      }
    }
  }
}

// ---- proj GEMM: out[m][n] = sum_k A[m][k]*W[n][k] + bias[n] (fp32) ----
// grid (8, 64), 256 thr.

__global__ __launch_bounds__(256) void gemm_proj(const u16* __restrict__ A,
                                                 const u16* __restrict__ W,
                                                 const float* __restrict__ bias,
                                                 float* __restrict__ outF) {
  __shared__ u16 sA[128 * 32];
  __shared__ u16 sB[128 * 32];

  const int K = 1024, N = 1024;
  const int t = threadIdx.x;
  const int lane = t & 63;
  const int w = t >> 6;
  const int wr = w >> 1, wc = w & 1;
  const int lr = lane & 15, lg = lane >> 4;

  int bid = blockIdx.y * 8 + blockIdx.x;
  int swz = (bid & 7) * 64 + (bid >> 3);
  const int mBase = (swz >> 3) * 128;
  const int nBase = (swz & 7) * 128;

  f32x4 zero = {0.f, 0.f, 0.f, 0.f};
  f32x4 acc[4][4];
#pragma unroll
  for (int i = 0; i < 4; ++i)
#pragma unroll
    for (int j = 0; j < 4; ++j) acc[i][j] = zero;

  const int rA = t >> 2;
  const int cA = (t & 3) * 8;

  for (int k0 = 0; k0 < K; k0 += 32) {
#pragma unroll
    for (int i = 0; i < 2; ++i) {
      gload_lds16(A + (size_t)(mBase + i * 64 + rA) * K + k0 + cA,
                  &sA[i * 2048 + t * 8]);
      gload_lds16(W + (size_t)(nBase + i * 64 + rA) * K + k0 + cA,
                  &sB[i * 2048 + t * 8]);
    }
    __syncthreads();

    bf16x8 af[4], bf[4];
#pragma unroll
    for (int i = 0; i < 4; ++i)
      af[i] = *(const bf16x8*)&sA[(wr * 64 + i * 16 + lr) * 32 + lg * 8];
#pragma unroll
    for (int j = 0; j < 4; ++j)
      bf[j] = *(const bf16x8*)&sB[(wc * 64 + j * 16 + lr) * 32 + lg * 8];

#pragma unroll
    for (int i = 0; i < 4; ++i)
#pragma unroll
      for (int j = 0; j < 4; ++j)
        acc[i][j] = __builtin_amdgcn_mfma_f32_16x16x32_bf16(af[i], bf[j],
                                                            acc[i][j], 0, 0, 0);
    __syncthreads();
  }

#pragma unroll
  for (int i = 0; i < 4; ++i) {
    int row = mBase + wr * 64 + i * 16 + lg * 4;
#pragma unroll
    for (int j = 0; j < 4; ++j) {
      int col = nBase + wc * 64 + j * 16 + lr;
      float bv = bias[col];
#pragma unroll
      for (int r = 0; r < 4; ++r)
        outF[(size_t)(row + r) * N + col] = acc[i][j][r] + bv;
    }
  }
}

// ---- causal flash attention ------------------------------------------
// q,k: bf16 [BH=64][T=2048][D=64]; vt: bf16 [BH=64][D=64][T=2048]
// y: bf16 [B=4][T=2048][C=1024]
// 512 thr (8 waves), Q tile = 128 rows (16/wave), KV tile = 128.
// Work-balanced: block p handles q-tiles {15-p&7 ...} -> uniform 17 KV-iters.
// Swapped QK^T -> lane-local softmax; P in registers (cvt_pk + shfl);
// defer-rescale; double-buffered LDS, parity via global tile counter.

__global__ __launch_bounds__(512, 4) void attn_fwd(const u16* __restrict__ qg,
                                                   const u16* __restrict__ kg,
                                                   const u16* __restrict__ vtg,
                                                   u16* __restrict__ yg) {
  __shared__ u16 sK[2][128 * 64];    // [key][d], XOR chunk swz by key&7
  __shared__ u16 sVt[2][64 * 128];   // [d][t],   XOR chunk swz by d&15

  const int t = threadIdx.x;
  const int lane = t & 63;
  const int w = t >> 6;
  const int lr = lane & 15, lg = lane >> 4;

  int bid0 = blockIdx.y * 8 + blockIdx.x;
  int swzb = (bid0 & 7) * 64 + (bid0 >> 3);
  const int bh = swzb >> 3;
  const int pair = swzb & 7;
  const size_t base = (size_t)bh * 2048 * 64;

  const u32* ks = (const u32*)(kg + base);    // [t][d] rows of 32 u32
  const u32* vs = (const u32*)(vtg + base);   // [d][t] rows of 1024 u32

  // prefetch KV tile 0 (128 keys): 8 u32 K + 8 u32 V per thread
  u32 kreg[8], vreg[8];
#pragma unroll
  for (int e = 0; e < 8; ++e) {
    int p = t + e * 512;
    kreg[e] = ks[p];
    vreg[e] = vs[(p >> 6) * 1024 + (p & 63)];
  }

  f32x4 zero = {0.f, 0.f, 0.f, 0.f};
  const int b = bh >> 4, h = bh & 15;
  int tc = 0;   // global tile counter -> LDS buffer parity

  for (int half = 0; half < 2; ++half) {
    const int qt = half ? pair : 15 - pair;
    const int nkt = qt + 1;
    const int wq0 = qt * 128 + w * 16;
    const int qrow = wq0 + lr;

    bf16x8 qf[2];
#pragma unroll
    for (int kk = 0; kk < 2; ++kk)
      qf[kk] = *(const bf16x8*)(qg + base + (size_t)qrow * 64 + kk * 32 + lg * 8);

    f32x4 accO[4];
#pragma unroll
    for (int n = 0; n < 4; ++n) accO[n] = zero;
    float mrun = -1e30f, lrun = 0.f;

    for (int kt = 0; kt < nkt; ++kt, ++tc) {
      char* kb_ = (char*)&sK[tc & 1][0];
      char* vb_ = (char*)&sVt[tc & 1][0];

      // stage current tile (conflict-free rows + XOR chunk swizzle)
#pragma unroll
      for (int e = 0; e < 8; ++e) {
        int p = t + e * 512;
        int kr = p >> 5, kd = p & 31;
        *(u32*)(kb_ + kr * 128 + ((kd * 4) ^ ((kr & 7) << 4))) = kreg[e];
        int vr = p >> 6, vd = p & 63;
        *(u32*)(vb_ + vr * 256 + ((vd * 4) ^ ((vr & 15) << 4))) = vreg[e];
      }

      // prefetch next tile (or tile 0 of second half)
      int nextT = (kt + 1 < nkt) ? kt + 1 : (half == 0 ? 0 : -1);
      if (nextT >= 0) {
        const u32* kn = ks + (size_t)nextT * 4096;
        const u32* vn = vs + nextT * 64;
#pragma unroll
        for (int e = 0; e < 8; ++e) {
          int p = t + e * 512;
          kreg[e] = kn[p];
          vreg[e] = vn[(p >> 6) * 1024 + (p & 63)];
        }
      }

      __syncthreads();

      // S^T = K Q^T : lane holds 32 P-values of q-row `qrow`
      f32x4 s[8];
      __builtin_amdgcn_s_setprio(1);
#pragma unroll
      for (int n = 0; n < 8; ++n) {
        f32x4 a = zero;
#pragma unroll
        for (int kk = 0; kk < 2; ++kk) {
          bf16x8 kf = *(const bf16x8*)(kb_ + (n * 16 + lr) * 128 +
                                       ((kk * 64 + lg * 16) ^ ((lr & 7) << 4)));
          a = __builtin_amdgcn_mfma_f32_16x16x32_bf16(kf, qf[kk], a, 0, 0, 0);
        }
        s[n] = a;
      }
      __builtin_amdgcn_s_setprio(0);

      // mask only the diagonal tile (kt == qt); scale pre-folded into Q
      if (kt == qt) {
#pragma unroll
        for (int n = 0; n < 8; ++n) {
          int key0 = kt * 128 + n * 16 + lg * 4;
#pragma unroll
          for (int r = 0; r < 4; ++r)
            s[n][r] = (key0 + r <= qrow) ? s[n][r] : -1e30f;
        }
      }

      // softmax: lane-local over 32 values + 2 shfls
      float pmax = -1e30f;
#pragma unroll
      for (int n = 0; n < 8; ++n)
        pmax = fmaxf(pmax, fmaxf(fmaxf(s[n][0], s[n][1]), fmaxf(s[n][2], s[n][3])));
      pmax = fmaxf(pmax, __shfl_xor(pmax, 16));
      pmax = fmaxf(pmax, __shfl_xor(pmax, 32));

      const bool full = __any(pmax > mrun + 8.f);
      float mnew = full ? fmaxf(mrun, pmax) : mrun;
      float corr = full ? exp2f(mrun - mnew) : 1.f;
      mrun = mnew;

      float psum = 0.f;
      u32 pk[8][2];
#pragma unroll
      for (int n = 0; n < 8; ++n) {
        float p0 = exp2f(s[n][0] - mnew);
        float p1 = exp2f(s[n][1] - mnew);
        float p2 = exp2f(s[n][2] - mnew);
        float p3 = exp2f(s[n][3] - mnew);
        psum += (p0 + p1) + (p2 + p3);
        pk[n][0] = cvtpk(p0, p1);
        pk[n][1] = cvtpk(p2, p3);
      }
      psum += __shfl_xor(psum, 16);
      psum += __shfl_xor(psum, 32);

      if (full) {
        lrun = lrun * corr + psum;
        float c4[4];
#pragma unroll
        for (int r = 0; r < 4; ++r) c4[r] = __shfl(corr, lg * 4 + r);
#pragma unroll
        for (int n = 0; n < 4; ++n)
#pragma unroll
          for (int r = 0; r < 4; ++r) accO[n][r] *= c4[r];
      } else {
        lrun += psum;
      }

      // O += P V : 4 K-steps of 32 keys; A-frags via shfl, B = V^T
      const bool hi = (lg >> 1) & 1;
#pragma unroll
      for (int kk = 0; kk < 4; ++kk) {
        u32 g[4];
#pragma unroll
        for (int r = 0; r < 4; ++r) {
          const int rh = r >> 1, rl = r & 1;
          u32 give = ((lg & 1) ^ rh) ? pk[2 * kk + 1][rl] : pk[2 * kk][rl];
          int srcLane = ((lg & 1) * 2 + ((lg >> 1) ^ rh)) * 16 + lr;
          g[r] = (u32)__shfl((int)give, srcLane);
        }
        union { u32 u[4]; bf16x8 v; } pu;
        pu.u[0] = hi ? g[2] : g[0];
        pu.u[1] = hi ? g[3] : g[1];
        pu.u[2] = hi ? g[0] : g[2];
        pu.u[3] = hi ? g[1] : g[3];
        bf16x8 pf = pu.v;
        __builtin_amdgcn_s_setprio(1);
#pragma unroll
        for (int n = 0; n < 4; ++n) {
          bf16x8 vf = *(const bf16x8*)(vb_ + (n * 16 + lr) * 256 +
                                       ((kk * 64 + lg * 16) ^ ((lr & 15) << 4)));
          accO[n] = __builtin_amdgcn_mfma_f32_16x16x32_bf16(pf, vf, accO[n], 0, 0, 0);
        }
        __builtin_amdgcn_s_setprio(0);
      }
    }

    // epilogue: accO rows q = lg*4+r; lrun lives at lane lr==q
#pragma unroll
    for (int r = 0; r < 4; ++r) {
      float linv = 1.f / __shfl(lrun, lg * 4 + r);
      int trow = qt * 128 + w * 16 + lg * 4 + r;
      size_t rowOff = ((size_t)b * 2048 + trow) * 1024 + h * 64;
#pragma unroll
      for (int n = 0; n < 4; ++n)
        yg[rowOff + n * 16 + lr] = f2b(accO[n][r] * linv);
    }
  }
}

// ---- launch -----------------------------------------------------------

extern "C" void kernel_launch(void* const* d_in, const int* in_sizes, int n_in,
                              void* d_out, int out_size, void* d_ws, size_t ws_size,
                              hipStream_t stream) {
  const float* x  = (const float*)d_in[0];
  const float* Wq = (const float*)d_in[1];
  const float* bq = (const float*)d_in[2];
  const float* Wk = (const float*)d_in[3];
  const float* bk = (const float*)d_in[4];
  const float* Wv = (const float*)d_in[5];
  const float* bv = (const float*)d_in[6];
  const float* Wp = (const float*)d_in[7];
  const float* bp = (const float*)d_in[8];
  float* out = (float*)d_out;

  char* ws = (char*)d_ws;
  u16* xb  = (u16*)(ws);                      // 16 MB  [8192][1024]
  u16* wqb = (u16*)(ws + (16u << 20));        // 2 MB each, wq|wk|wv|wp contiguous
  u16* wpb = (u16*)(ws + (22u << 20));
  u16* qb  = (u16*)(ws + (24u << 20));        // 16 MB [bh][t][d]
  u16* kb  = (u16*)(ws + (40u << 20));        // 16 MB [bh][t][d]
  u16* vtb = (u16*)(ws + (56u << 20));        // 16 MB [bh][d][t]
  u16* yb  = (u16*)(ws + (72u << 20));        // 16 MB [8192][1024]

  const float SCL = 0.18033688011112042f;     // 0.125 * log2(e)

  // fp32 -> bf16 (x + all weights, one dispatch)
  cvt_all<<<12288, 256, 0, stream>>>(x, Wq, Wk, Wv, Wp, xb, wqb);

  // fused QKV projection (Q pre-scaled by SCL)
  gemm_qkv<<<dim3(24, 64), 256, 0, stream>>>(xb, wqb, bq, bk, bv,
                                             qb, kb, vtb, SCL);

  // causal attention -> y bf16 [B,T,C]
  attn_fwd<<<dim3(8, 64), 512, 0, stream>>>(qb, kb, vtb, yb);

  // output projection -> fp32 d_out
  gemm_proj<<<dim3(8, 64), 256, 0, stream>>>(yb, wpb, bp, out);
}

// Round 7
// 208.766 us; speedup vs baseline: 1.0677x; 1.0677x over previous
//
#include <hip/hip_runtime.h>

typedef unsigned short u16;
typedef unsigned int u32;

typedef __attribute__((ext_vector_type(4))) float f32x4;
typedef __attribute__((ext_vector_type(8))) short bf16x8;

// ---- helpers ----------------------------------------------------------

__device__ inline u16 f2b(float f) {
  union { float f; u32 u; } x; x.f = f;
  u32 u = x.u;
  u32 r = (u + 0x7fffu + ((u >> 16) & 1u)) >> 16;   // round-nearest-even
  return (u16)r;
}

__device__ inline u32 cvtpk(float lo, float hi) {
  u32 r;
  asm("v_cvt_pk_bf16_f32 %0, %1, %2" : "=v"(r) : "v"(lo), "v"(hi));
  return r;
}

__device__ inline void gload_lds16(const void* g, void* l) {
  __builtin_amdgcn_global_load_lds(
      (const __attribute__((address_space(1))) u32*)g,
      (__attribute__((address_space(3))) u32*)l, 16, 0, 0);
}

// ---- fp32 -> bf16 convert (x + 4 weights in one dispatch) -------------
// blocks [0,8192): x ; [8192,12288): weights (wq|wk|wv|wp contiguous)

__global__ __launch_bounds__(256) void cvt_all(const float* __restrict__ x,
                                               const float* __restrict__ w0,
                                               const float* __restrict__ w1,
                                               const float* __restrict__ w2,
                                               const float* __restrict__ w3,
                                               u16* __restrict__ xo,
                                               u16* __restrict__ wo) {
  int b = blockIdx.x;
  const float* s;
  u16* d;
  int i;
  if (b < 8192) {
    s = x; d = xo; i = b * 256 + threadIdx.x;
  } else {
    int m = (b - 8192) >> 10;
    s = (m == 0) ? w0 : (m == 1) ? w1 : (m == 2) ? w2 : w3;
    d = wo + (size_t)m * 1048576;
    i = ((b - 8192) & 1023) * 256 + threadIdx.x;
  }
  float4 v = ((const float4*)s)[i];
  ushort4 o;
  o.x = f2b(v.x); o.y = f2b(v.y); o.z = f2b(v.z); o.w = f2b(v.w);
  ((ushort4*)d)[i] = o;
}

// ---- fused QKV GEMM ----------------------------------------------------
// A[8192][1024] bf16, W[3072][1024] bf16 (wq|wk|wv rows).
// col<1024 -> Q bf16 [bh][t][d] scaled by qscale; col<2048 -> K same layout;
// col>=2048 -> V^T bf16 [bh][d][t] (ushort4-packed along t).
// grid (24, 64), 256 thr.

__global__ __launch_bounds__(256) void gemm_qkv(const u16* __restrict__ A,
                                                const u16* __restrict__ W,
                                                const float* __restrict__ bq,
                                                const float* __restrict__ bk,
                                                const float* __restrict__ bv,
                                                u16* __restrict__ outQ,
                                                u16* __restrict__ outK,
                                                u16* __restrict__ outVt,
                                                float qscale) {
  __shared__ u16 sA[128 * 32];
  __shared__ u16 sB[128 * 32];

  const int K = 1024;
  const int t = threadIdx.x;
  const int lane = t & 63;
  const int w = t >> 6;
  const int wr = w >> 1, wc = w & 1;
  const int lr = lane & 15, lg = lane >> 4;

  // bijective XCD-chunked swizzle (1536 blocks, 1536%8==0)
  int bid = blockIdx.y * 24 + blockIdx.x;
  int swz = (bid & 7) * 192 + (bid >> 3);
  const int mBase = (swz / 24) * 128;
  const int nBase = (swz % 24) * 128;

  f32x4 zero = {0.f, 0.f, 0.f, 0.f};
  f32x4 acc[4][4];
#pragma unroll
  for (int i = 0; i < 4; ++i)
#pragma unroll
    for (int j = 0; j < 4; ++j) acc[i][j] = zero;

  const int rA = t >> 2;
  const int cA = (t & 3) * 8;

  for (int k0 = 0; k0 < K; k0 += 32) {
#pragma unroll
    for (int i = 0; i < 2; ++i) {
      gload_lds16(A + (size_t)(mBase + i * 64 + rA) * K + k0 + cA,
                  &sA[i * 2048 + t * 8]);
      gload_lds16(W + (size_t)(nBase + i * 64 + rA) * K + k0 + cA,
                  &sB[i * 2048 + t * 8]);
    }
    __syncthreads();

    bf16x8 af[4], bf[4];
#pragma unroll
    for (int i = 0; i < 4; ++i)
      af[i] = *(const bf16x8*)&sA[(wr * 64 + i * 16 + lr) * 32 + lg * 8];
#pragma unroll
    for (int j = 0; j < 4; ++j)
      bf[j] = *(const bf16x8*)&sB[(wc * 64 + j * 16 + lr) * 32 + lg * 8];

#pragma unroll
    for (int i = 0; i < 4; ++i)
#pragma unroll
      for (int j = 0; j < 4; ++j)
        acc[i][j] = __builtin_amdgcn_mfma_f32_16x16x32_bf16(af[i], bf[j],
                                                            acc[i][j], 0, 0, 0);
    __syncthreads();
  }

  const int mode = nBase >> 10;       // 0=Q 1=K 2=V
  const float* bias = (mode == 0) ? bq : (mode == 1) ? bk : bv;
  const float scl = (mode == 0) ? qscale : 1.f;

#pragma unroll
  for (int i = 0; i < 4; ++i) {
    int row = mBase + wr * 64 + i * 16 + lg * 4;     // row % 4 == 0
    int b = row >> 11, tp = row & 2047;
#pragma unroll
    for (int j = 0; j < 4; ++j) {
      int col = nBase + wc * 64 + j * 16 + lr;
      int ncol = col & 1023;
      int h = ncol >> 6, dd = ncol & 63;
      float bv_ = bias[ncol];
      if (mode == 2) {
        ushort4 o;
        o.x = f2b(acc[i][j][0] + bv_);
        o.y = f2b(acc[i][j][1] + bv_);
        o.z = f2b(acc[i][j][2] + bv_);
        o.w = f2b(acc[i][j][3] + bv_);
        *(ushort4*)(outVt + ((size_t)((b * 16 + h) * 64 + dd)) * 2048 + tp) = o;
      } else {
        u16* ob = (mode == 0) ? outQ : outK;
#pragma unroll
        for (int r = 0; r < 4; ++r)
          ob[(((size_t)(b * 16 + h) * 2048) + tp + r) * 64 + dd] =
              f2b((acc[i][j][r] + bv_) * scl);
      }
    }
  }
}

// ---- proj GEMM: out[m][n] = sum_k A[m][k]*W[n][k] + bias[n] (fp32) ----
// grid (8, 64), 256 thr.

__global__ __launch_bounds__(256) void gemm_proj(const u16* __restrict__ A,
                                                 const u16* __restrict__ W,
                                                 const float* __restrict__ bias,
                                                 float* __restrict__ outF) {
  __shared__ u16 sA[128 * 32];
  __shared__ u16 sB[128 * 32];

  const int K = 1024, N = 1024;
  const int t = threadIdx.x;
  const int lane = t & 63;
  const int w = t >> 6;
  const int wr = w >> 1, wc = w & 1;
  const int lr = lane & 15, lg = lane >> 4;

  int bid = blockIdx.y * 8 + blockIdx.x;
  int swz = (bid & 7) * 64 + (bid >> 3);
  const int mBase = (swz >> 3) * 128;
  const int nBase = (swz & 7) * 128;

  f32x4 zero = {0.f, 0.f, 0.f, 0.f};
  f32x4 acc[4][4];
#pragma unroll
  for (int i = 0; i < 4; ++i)
#pragma unroll
    for (int j = 0; j < 4; ++j) acc[i][j] = zero;

  const int rA = t >> 2;
  const int cA = (t & 3) * 8;

  for (int k0 = 0; k0 < K; k0 += 32) {
#pragma unroll
    for (int i = 0; i < 2; ++i) {
      gload_lds16(A + (size_t)(mBase + i * 64 + rA) * K + k0 + cA,
                  &sA[i * 2048 + t * 8]);
      gload_lds16(W + (size_t)(nBase + i * 64 + rA) * K + k0 + cA,
                  &sB[i * 2048 + t * 8]);
    }
    __syncthreads();

    bf16x8 af[4], bf[4];
#pragma unroll
    for (int i = 0; i < 4; ++i)
      af[i] = *(const bf16x8*)&sA[(wr * 64 + i * 16 + lr) * 32 + lg * 8];
#pragma unroll
    for (int j = 0; j < 4; ++j)
      bf[j] = *(const bf16x8*)&sB[(wc * 64 + j * 16 + lr) * 32 + lg * 8];

#pragma unroll
    for (int i = 0; i < 4; ++i)
#pragma unroll
      for (int j = 0; j < 4; ++j)
        acc[i][j] = __builtin_amdgcn_mfma_f32_16x16x32_bf16(af[i], bf[j],
                                                            acc[i][j], 0, 0, 0);
    __syncthreads();
  }

#pragma unroll
  for (int i = 0; i < 4; ++i) {
    int row = mBase + wr * 64 + i * 16 + lg * 4;
#pragma unroll
    for (int j = 0; j < 4; ++j) {
      int col = nBase + wc * 64 + j * 16 + lr;
      float bv = bias[col];
#pragma unroll
      for (int r = 0; r < 4; ++r)
        outF[(size_t)(row + r) * N + col] = acc[i][j][r] + bv;
    }
  }
}

// ---- causal flash attention ------------------------------------------
// q,k: bf16 [BH=64][T=2048][D=64]; vt: bf16 [BH=64][D=64][T=2048]
// y: bf16 [B=4][T=2048][C=1024]
// 512 thr (8 waves), Q tile = 128 rows (16/wave).
// KV tile = 128 keys staged per barrier; computed as TWO 64-key sub-steps
// (keeps round-5 register footprint -> no spills under the 128-VGPR cap).
// Work-balanced pairing {15-p, p}. Swapped QK^T, in-register P,
// defer-rescale, double-buffered LDS (parity = global tile counter).

__global__ __launch_bounds__(512, 4) void attn_fwd(const u16* __restrict__ qg,
                                                   const u16* __restrict__ kg,
                                                   const u16* __restrict__ vtg,
                                                   u16* __restrict__ yg) {
  __shared__ u16 sK[2][128 * 64];    // [key][d],  XOR chunk swz by key&7
  __shared__ u16 sVt[2][64 * 128];   // [d][t128], XOR chunk swz by d&15

  const int t = threadIdx.x;
  const int lane = t & 63;
  const int w = t >> 6;
  const int lr = lane & 15, lg = lane >> 4;

  int bid0 = blockIdx.y * 8 + blockIdx.x;
  int swzb = (bid0 & 7) * 64 + (bid0 >> 3);
  const int bh = swzb >> 3;
  const int pair = swzb & 7;
  const size_t base = (size_t)bh * 2048 * 64;

  const u32* ks = (const u32*)(kg + base);    // [t][d]: rows of 32 u32
  const u32* vs = (const u32*)(vtg + base);   // [d][t]: rows of 1024 u32

  // prefetch KV tile 0 (128 keys): 8 u32 K + 8 u32 V per thread
  u32 kreg[8], vreg[8];
#pragma unroll
  for (int e = 0; e < 8; ++e) {
    int p = t + e * 512;
    kreg[e] = ks[p];
    vreg[e] = vs[(p >> 6) * 1024 + (p & 63)];
  }

  f32x4 zero = {0.f, 0.f, 0.f, 0.f};
  const int b = bh >> 4, h = bh & 15;
  int tc = 0;   // global tile counter -> LDS buffer parity

  for (int half = 0; half < 2; ++half) {
    const int qt = half ? pair : 15 - pair;
    const int nkt = qt + 1;
    const int wq0 = qt * 128 + w * 16;
    const int qrow = wq0 + lr;

    bf16x8 qf[2];
#pragma unroll
    for (int kk = 0; kk < 2; ++kk)
      qf[kk] = *(const bf16x8*)(qg + base + (size_t)qrow * 64 + kk * 32 + lg * 8);

    f32x4 accO[4];
#pragma unroll
    for (int n = 0; n < 4; ++n) accO[n] = zero;
    float mrun = -1e30f, lrun = 0.f;

    for (int kt = 0; kt < nkt; ++kt, ++tc) {
      char* kb_ = (char*)&sK[tc & 1][0];
      char* vb_ = (char*)&sVt[tc & 1][0];

      // stage current 128-key tile (conflict-free rows + XOR chunk swizzle)
#pragma unroll
      for (int e = 0; e < 8; ++e) {
        int p = t + e * 512;
        int kr = p >> 5, kd = p & 31;
        *(u32*)(kb_ + kr * 128 + ((kd * 4) ^ ((kr & 7) << 4))) = kreg[e];
        int vr = p >> 6, vd = p & 63;
        *(u32*)(vb_ + vr * 256 + ((vd * 4) ^ ((vr & 15) << 4))) = vreg[e];
      }

      // prefetch next tile (or tile 0 of second half)
      int nextT = (kt + 1 < nkt) ? kt + 1 : (half == 0 ? 0 : -1);
      if (nextT >= 0) {
        const u32* kn = ks + (size_t)nextT * 4096;
        const u32* vn = vs + nextT * 64;
#pragma unroll
        for (int e = 0; e < 8; ++e) {
          int p = t + e * 512;
          kreg[e] = kn[p];
          vreg[e] = vn[(p >> 6) * 1024 + (p & 63)];
        }
      }

      __syncthreads();

      // two 64-key sub-steps over the staged 128-key tile
      for (int sub = 0; sub < 2; ++sub) {
        const int key0g = kt * 128 + sub * 64;
        const bool diag = (kt == qt);
        if (diag && key0g > wq0 + 15) continue;   // fully masked (wave-uniform)

        // S^T = K Q^T : lane holds 16 P-values of q-row `qrow`
        f32x4 s[4];
        __builtin_amdgcn_s_setprio(1);
#pragma unroll
        for (int n = 0; n < 4; ++n) {
          f32x4 a = zero;
          const int krow = sub * 64 + n * 16 + lr;
#pragma unroll
          for (int kk = 0; kk < 2; ++kk) {
            bf16x8 kf = *(const bf16x8*)(kb_ + krow * 128 +
                                         ((kk * 64 + lg * 16) ^ ((lr & 7) << 4)));
            a = __builtin_amdgcn_mfma_f32_16x16x32_bf16(kf, qf[kk], a, 0, 0, 0);
          }
          s[n] = a;
        }
        __builtin_amdgcn_s_setprio(0);

        // mask (diagonal sub-steps only; scale pre-folded into Q)
        if (diag && key0g + 63 > wq0) {
#pragma unroll
          for (int n = 0; n < 4; ++n) {
            int key0 = key0g + n * 16 + lg * 4;
#pragma unroll
            for (int r = 0; r < 4; ++r)
              s[n][r] = (key0 + r <= qrow) ? s[n][r] : -1e30f;
          }
        }

        // softmax: lane-local over 16 values + 2 shfls
        float pmax = -1e30f;
#pragma unroll
        for (int n = 0; n < 4; ++n)
          pmax = fmaxf(pmax, fmaxf(fmaxf(s[n][0], s[n][1]), fmaxf(s[n][2], s[n][3])));
        pmax = fmaxf(pmax, __shfl_xor(pmax, 16));
        pmax = fmaxf(pmax, __shfl_xor(pmax, 32));

        const bool full = __any(pmax > mrun + 8.f);
        float mnew = full ? fmaxf(mrun, pmax) : mrun;
        float corr = full ? exp2f(mrun - mnew) : 1.f;
        mrun = mnew;

        float psum = 0.f;
        u32 pk[4][2];
#pragma unroll
        for (int n = 0; n < 4; ++n) {
          float p0 = exp2f(s[n][0] - mnew);
          float p1 = exp2f(s[n][1] - mnew);
          float p2 = exp2f(s[n][2] - mnew);
          float p3 = exp2f(s[n][3] - mnew);
          psum += (p0 + p1) + (p2 + p3);
          pk[n][0] = cvtpk(p0, p1);
          pk[n][1] = cvtpk(p2, p3);
        }
        psum += __shfl_xor(psum, 16);
        psum += __shfl_xor(psum, 32);

        if (full) {
          lrun = lrun * corr + psum;
          float c4[4];
#pragma unroll
          for (int r = 0; r < 4; ++r) c4[r] = __shfl(corr, lg * 4 + r);
#pragma unroll
          for (int n = 0; n < 4; ++n)
#pragma unroll
            for (int r = 0; r < 4; ++r) accO[n][r] *= c4[r];
        } else {
          lrun += psum;
        }

        // O += P V : A-frags via shfl, B = V^T
        const bool hi = (lg >> 1) & 1;
#pragma unroll
        for (int kk = 0; kk < 2; ++kk) {
          u32 g[4];
#pragma unroll
          for (int r = 0; r < 4; ++r) {
            const int rh = r >> 1, rl = r & 1;
            u32 give = ((lg & 1) ^ rh) ? pk[2 * kk + 1][rl] : pk[2 * kk][rl];
            int srcLane = ((lg & 1) * 2 + ((lg >> 1) ^ rh)) * 16 + lr;
            g[r] = (u32)__shfl((int)give, srcLane);
          }
          union { u32 u[4]; bf16x8 v; } pu;
          pu.u[0] = hi ? g[2] : g[0];
          pu.u[1] = hi ? g[3] : g[1];
          pu.u[2] = hi ? g[0] : g[2];
          pu.u[3] = hi ? g[1] : g[3];
          bf16x8 pf = pu.v;
          __builtin_amdgcn_s_setprio(1);
#pragma unroll
          for (int n = 0; n < 4; ++n) {
            bf16x8 vf = *(const bf16x8*)(vb_ + (n * 16 + lr) * 256 +
                                         ((sub * 128 + kk * 64 + lg * 16) ^
                                          ((lr & 15) << 4)));
            accO[n] = __builtin_amdgcn_mfma_f32_16x16x32_bf16(pf, vf, accO[n], 0, 0, 0);
          }
          __builtin_amdgcn_s_setprio(0);
        }
      }
    }

    // epilogue: accO rows q = lg*4+r; lrun lives at lane lr==q
#pragma unroll
    for (int r = 0; r < 4; ++r) {
      float linv = 1.f / __shfl(lrun, lg * 4 + r);
      int trow = qt * 128 + w * 16 + lg * 4 + r;
      size_t rowOff = ((size_t)b * 2048 + trow) * 1024 + h * 64;
#pragma unroll
      for (int n = 0; n < 4; ++n)
        yg[rowOff + n * 16 + lr] = f2b(accO[n][r] * linv);
    }
  }
}

// ---- launch -----------------------------------------------------------

extern "C" void kernel_launch(void* const* d_in, const int* in_sizes, int n_in,
                              void* d_out, int out_size, void* d_ws, size_t ws_size,
                              hipStream_t stream) {
  const float* x  = (const float*)d_in[0];
  const float* Wq = (const float*)d_in[1];
  const float* bq = (const float*)d_in[2];
  const float* Wk = (const float*)d_in[3];
  const float* bk = (const float*)d_in[4];
  const float* Wv = (const float*)d_in[5];
  const float* bv = (const float*)d_in[6];
  const float* Wp = (const float*)d_in[7];
  const float* bp = (const float*)d_in[8];
  float* out = (float*)d_out;

  char* ws = (char*)d_ws;
  u16* xb  = (u16*)(ws);                      // 16 MB  [8192][1024]
  u16* wqb = (u16*)(ws + (16u << 20));        // 2 MB each, wq|wk|wv|wp contiguous
  u16* wpb = (u16*)(ws + (22u << 20));
  u16* qb  = (u16*)(ws + (24u << 20));        // 16 MB [bh][t][d]
  u16* kb  = (u16*)(ws + (40u << 20));        // 16 MB [bh][t][d]
  u16* vtb = (u16*)(ws + (56u << 20));        // 16 MB [bh][d][t]
  u16* yb  = (u16*)(ws + (72u << 20));        // 16 MB [8192][1024]

  const float SCL = 0.18033688011112042f;     // 0.125 * log2(e)

  // fp32 -> bf16 (x + all weights, one dispatch)
  cvt_all<<<12288, 256, 0, stream>>>(x, Wq, Wk, Wv, Wp, xb, wqb);

  // fused QKV projection (Q pre-scaled by SCL)
  gemm_qkv<<<dim3(24, 64), 256, 0, stream>>>(xb, wqb, bq, bk, bv,
                                             qb, kb, vtb, SCL);

  // causal attention -> y bf16 [B,T,C]
  attn_fwd<<<dim3(8, 64), 512, 0, stream>>>(qb, kb, vtb, yb);

  // output projection -> fp32 d_out
  gemm_proj<<<dim3(8, 64), 256, 0, stream>>>(yb, wpb, bp, out);
}